// Round 1
// baseline (450.411 us; speedup 1.0000x reference)
//
#include <hip/hip_runtime.h>

#define NE 128
#define NI 32
#define NT 160   // NE + NI
#define NC 10
#define BB 512
#define LL 64
#define DD 784
#define MM (BB*LL)

// ws layout (float offsets)
#define G_OFF   0
#define G_SZ    (NT*NT)            // 25600
#define WXT_OFF (G_OFF + G_SZ)
#define WXT_SZ  (DD*NT)            // 125440
#define U_OFF   (WXT_OFF + WXT_SZ) // 151040
#define U_SZ    (MM*NT)            // 5242880

// out layout (float offsets)
#define O_LOGITS 0
#define O_LAST   327680
#define O_RE     332800
#define O_RI     4527104
#define O_BALE   5575680
#define O_BALI   9769984

// ---------------------------------------------------------------------------
// Prep: build Dale-rectified combined recurrent matrix G[k][j] (j contiguous)
// and transposed rectified input weights WxT[d][j].
//   out_j = sum_k r[k] * G[k][j];  k<128 -> r_e, k>=128 -> r_i (negated inh)
// ---------------------------------------------------------------------------
__global__ void prep_kernel(const float* __restrict__ Wxe, const float* __restrict__ Wxi,
                            const float* __restrict__ Wee, const float* __restrict__ Wie,
                            const float* __restrict__ Wei, const float* __restrict__ Wii,
                            float* __restrict__ ws) {
  int idx = blockIdx.x * blockDim.x + threadIdx.x;
  const int total = G_SZ + WXT_SZ;
  if (idx >= total) return;
  if (idx < G_SZ) {
    int k = idx / NT, j = idx % NT;
    float g;
    if (j < NE) {
      if (k < NE) g =  fmaxf(Wee[j*NE + k], 0.f);
      else        g = -fmaxf(Wie[j*NI + (k-NE)], 0.f);
    } else {
      int ji = j - NE;
      if (k < NE) g =  fmaxf(Wei[ji*NE + k], 0.f);
      else        g = -fmaxf(Wii[ji*NI + (k-NE)], 0.f);
    }
    ws[G_OFF + k*NT + j] = g;
  } else {
    int t = idx - G_SZ;
    int d = t / NT, j = t % NT;
    float v = (j < NE) ? fmaxf(Wxe[j*DD + d], 0.f)
                       : fmaxf(Wxi[(j-NE)*DD + d], 0.f);
    ws[WXT_OFF + d*NT + j] = v;
  }
}

// ---------------------------------------------------------------------------
// GEMM: U[m][j] = sum_d X[m][d] * WxT[d][j],  M=32768, K=784, N=160.
// 256 blocks x 256 threads; tile 128 rows x 160 cols; K chunks of 56.
// Thread (ty,tx) computes 8 rows x 10 cols. fp32 (compute-bound ~52us floor).
// ---------------------------------------------------------------------------
#define KT 56
__global__ __launch_bounds__(256, 1) void gemm_kernel(const float* __restrict__ X,
                                                      const float* __restrict__ ws,
                                                      float* __restrict__ U) {
  __shared__ float xs[128 * KT];            // [row][k], 28672 B
  __shared__ float wt4[(KT/4) * NT * 4];    // [k4][j][4], 35840 B  (float4 along k)
  const int tid = threadIdx.x;
  const int tx = tid & 15, ty = tid >> 4;
  const int m0 = blockIdx.x * 128;
  const float* WxT = ws + WXT_OFF;

  float acc[8][10];
  #pragma unroll
  for (int i = 0; i < 8; ++i)
    #pragma unroll
    for (int c = 0; c < 10; ++c) acc[i][c] = 0.f;

  for (int t = 0; t < DD/KT; ++t) {
    const int k0 = t * KT;
    __syncthreads();
    // stage x tile (float4)
    for (int i = tid; i < 128*(KT/4); i += 256) {
      int r = i / (KT/4), c4 = i % (KT/4);
      float4 v = *(const float4*)(X + (size_t)(m0 + r)*DD + k0 + c4*4);
      *(float4*)(xs + r*KT + c4*4) = v;
    }
    // stage W tile repacked as [k4][j][4]
    for (int i = tid; i < KT*(NT/4); i += 256) {
      int d = i / (NT/4), j4 = i % (NT/4);
      float4 v = *(const float4*)(WxT + (size_t)(k0 + d)*NT + j4*4);
      int d4 = d >> 2, dd = d & 3;
      float* base = wt4 + ((d4*NT + j4*4) << 2) + dd;
      base[0] = v.x; base[4] = v.y; base[8] = v.z; base[12] = v.w;
    }
    __syncthreads();
    for (int kk4 = 0; kk4 < KT/4; ++kk4) {
      float4 xv[8];
      float4 wv[10];
      #pragma unroll
      for (int i = 0; i < 8; ++i)
        xv[i] = *(const float4*)(xs + (ty*8 + i)*KT + kk4*4);
      #pragma unroll
      for (int c = 0; c < 10; ++c)
        wv[c] = *(const float4*)(wt4 + ((kk4*NT + tx*10 + c) << 2));
      #pragma unroll
      for (int i = 0; i < 8; ++i)
        #pragma unroll
        for (int c = 0; c < 10; ++c)
          acc[i][c] += xv[i].x*wv[c].x + xv[i].y*wv[c].y
                     + xv[i].z*wv[c].z + xv[i].w*wv[c].w;
    }
  }
  #pragma unroll
  for (int i = 0; i < 8; ++i)
    #pragma unroll
    for (int c = 0; c < 10; ++c)
      U[(size_t)(m0 + ty*8 + i)*NT + tx*10 + c] = acc[i][c];
}

// ---------------------------------------------------------------------------
// Recurrent scan. 256 blocks x 256 threads, 2 batch rows per block.
// G held in registers: thread owns G[k0..k0+20)[j0..j0+5).
// lane = kc*8 + jc3 (kc = k-chunk 0..7); jc = wave*8 + jc3 (j-chunk 0..31).
// Partial dots reduced over kc via shfl_xor(8,16,32). Lanes kc<2 own rows.
// ---------------------------------------------------------------------------
__global__ __launch_bounds__(256, 1) void recur_kernel(
    const float* __restrict__ ws,
    const float* __restrict__ be, const float* __restrict__ bi,
    const float* __restrict__ Wro, const float* __restrict__ bro,
    float* __restrict__ out) {
  __shared__ float rbuf[2][NT];
  __shared__ float balbuf[2][NT];
  __shared__ float WroL[NC*NE];
  __shared__ float biasL[NT];
  __shared__ float broL[NC];

  const int tid  = threadIdx.x;
  const int lane = tid & 63;
  const int wave = tid >> 6;
  const int jc   = (wave << 3) | (lane & 7);  // 0..31
  const int kc   = (lane >> 3) & 7;           // 0..7
  const int j0   = jc * 5;
  const int k0   = kc * 20;
  const int b0   = blockIdx.x * 2;

  const float* G = ws + G_OFF;
  const float* U = ws + U_OFF;

  // G slice -> registers (100 VGPRs)
  float g[20][5];
  #pragma unroll
  for (int kk = 0; kk < 20; ++kk)
    #pragma unroll
    for (int c = 0; c < 5; ++c)
      g[kk][c] = G[(size_t)(k0 + kk)*NT + j0 + c];

  for (int i = tid; i < NC*NE; i += 256) WroL[i] = Wro[i];
  if (tid < NT) biasL[tid] = (tid < NE) ? be[tid] : bi[tid - NE];
  if (tid < NC) broL[tid] = bro[tid];
  for (int i = tid; i < 2*NT; i += 256) (&rbuf[0][0])[i] = 0.f;

  float s[5];
  #pragma unroll
  for (int c = 0; c < 5; ++c) s[c] = 0.f;

  float* out_logits = out + O_LOGITS;
  float* out_last   = out + O_LAST;
  float* out_re     = out + O_RE;
  float* out_ri     = out + O_RI;
  float* out_bale   = out + O_BALE;
  float* out_bali   = out + O_BALI;

  __syncthreads();

  for (int l = 0; l < LL; ++l) {
    // 1. partial recurrent dots for both rows over this thread's k-chunk
    float a0[5], a1[5];
    #pragma unroll
    for (int c = 0; c < 5; ++c) { a0[c] = 0.f; a1[c] = 0.f; }
    #pragma unroll
    for (int kk4 = 0; kk4 < 5; ++kk4) {
      float4 rv0 = *(const float4*)(&rbuf[0][k0 + kk4*4]);
      float4 rv1 = *(const float4*)(&rbuf[1][k0 + kk4*4]);
      #pragma unroll
      for (int c = 0; c < 5; ++c) {
        a0[c] += rv0.x*g[kk4*4+0][c] + rv0.y*g[kk4*4+1][c]
               + rv0.z*g[kk4*4+2][c] + rv0.w*g[kk4*4+3][c];
        a1[c] += rv1.x*g[kk4*4+0][c] + rv1.y*g[kk4*4+1][c]
               + rv1.z*g[kk4*4+2][c] + rv1.w*g[kk4*4+3][c];
      }
    }
    // 2. butterfly reduce over kc (lane bits 3..5)
    #pragma unroll
    for (int c = 0; c < 5; ++c) {
      float v0 = a0[c], v1 = a1[c];
      v0 += __shfl_xor(v0, 8, 64);  v1 += __shfl_xor(v1, 8, 64);
      v0 += __shfl_xor(v0, 16, 64); v1 += __shfl_xor(v1, 16, 64);
      v0 += __shfl_xor(v0, 32, 64); v1 += __shfl_xor(v1, 32, 64);
      a0[c] = v0; a1[c] = v1;
    }
    __syncthreads();   // all reads of rbuf done
    // 3. owner lanes (kc<2 -> row=kc) update state, write r/bal to LDS
    if (kc < 2) {
      const int row = kc;
      const int b = b0 + row;
      const size_t ubase = ((size_t)b*LL + l)*NT + j0;
      #pragma unroll
      for (int c = 0; c < 5; ++c) {
        float accv = (kc == 0) ? a0[c] : a1[c];
        float bal = accv + U[ubase + c];
        balbuf[row][j0 + c] = bal;
        float sn = 0.5f*(s[c] + bal + biasL[j0 + c]);
        s[c] = sn;
        rbuf[row][j0 + c] = fmaxf(sn, 0.f);
      }
    }
    __syncthreads();   // rbuf/balbuf now hold t=l+1 rates and step-l balances
    // 4a. coalesced global writes
    {
      const int row = tid >> 7, jj = tid & 127;
      const size_t ob = (size_t)(b0 + row)*LL + l;
      out_re[ob*NE + jj]   = rbuf[row][jj];
      out_bale[ob*NE + jj] = balbuf[row][jj];
      if (tid < 64) {
        const int row2 = tid >> 5, j2 = tid & 31;
        const size_t ob2 = (size_t)(b0 + row2)*LL + l;
        out_ri[ob2*NI + j2]   = rbuf[row2][NE + j2];
        out_bali[ob2*NI + j2] = balbuf[row2][NE + j2];
      }
    }
    // 4b. logits = relu(e_new) @ Wro^T + bro ; 8 lanes per (row,class)
    if (tid < 160) {
      const int p = tid >> 3, q = tid & 7;
      const int row = p / 10, c = p % 10;
      float v = 0.f;
      #pragma unroll
      for (int t4 = 0; t4 < 4; ++t4) {
        float4 rv = *(const float4*)(&rbuf[row][q*16 + t4*4]);
        float4 wv = *(const float4*)(&WroL[c*NE + q*16 + t4*4]);
        v += rv.x*wv.x + rv.y*wv.y + rv.z*wv.z + rv.w*wv.w;
      }
      v += __shfl_xor(v, 1, 64);
      v += __shfl_xor(v, 2, 64);
      v += __shfl_xor(v, 4, 64);
      if (q == 0) {
        float lg = v + broL[c];
        out_logits[((size_t)(b0 + row)*LL + l)*NC + c] = lg;
        if (l == LL - 1) out_last[(size_t)(b0 + row)*NC + c] = lg;
      }
    }
  }
}

extern "C" void kernel_launch(void* const* d_in, const int* in_sizes, int n_in,
                              void* d_out, int out_size, void* d_ws, size_t ws_size,
                              hipStream_t stream) {
  const float* x   = (const float*)d_in[0];
  const float* Wxe = (const float*)d_in[1];
  const float* Wxi = (const float*)d_in[2];
  const float* Wee = (const float*)d_in[3];
  const float* Wie = (const float*)d_in[4];
  const float* Wei = (const float*)d_in[5];
  const float* Wii = (const float*)d_in[6];
  const float* be  = (const float*)d_in[7];
  const float* bi  = (const float*)d_in[8];
  const float* Wro = (const float*)d_in[9];
  const float* bro = (const float*)d_in[10];
  float* ws  = (float*)d_ws;
  float* out = (float*)d_out;

  hipLaunchKernelGGL(prep_kernel, dim3((G_SZ + WXT_SZ + 255)/256), dim3(256), 0, stream,
                     Wxe, Wxi, Wee, Wie, Wei, Wii, ws);
  hipLaunchKernelGGL(gemm_kernel, dim3(MM/128), dim3(256), 0, stream,
                     x, ws, ws + U_OFF);
  hipLaunchKernelGGL(recur_kernel, dim3(BB/2), dim3(256), 0, stream,
                     ws, be, bi, Wro, bro, out);
}